// Round 1
// baseline (10628.783 us; speedup 1.0000x reference)
//
#include <hip/hip_runtime.h>
#include <math.h>

#define NN 100000
#define NE 1000000
#define H 64

static __device__ __forceinline__ float relu_(float x){ return fmaxf(x, 0.0f); }

// ---------------- encoder: h = relu(relu(x@w1+b1)@w2+b2), x:[N,5] ----------------
__global__ __launch_bounds__(256) void enc_kernel(
    const float* __restrict__ x,
    const float* __restrict__ w1, const float* __restrict__ b1,
    const float* __restrict__ w2, const float* __restrict__ b2,
    float* __restrict__ h)
{
  int v = blockIdx.x*256 + threadIdx.x;
  if (v >= NN) return;
  float in0[5];
  #pragma unroll
  for (int k=0;k<5;k++) in0[k] = x[v*5+k];
  float hid[H];
  #pragma unroll
  for (int j=0;j<H;j++) hid[j] = b1[j];
  #pragma unroll
  for (int k=0;k<5;k++){
    #pragma unroll
    for (int j=0;j<H;j++) hid[j] = fmaf(in0[k], w1[k*H+j], hid[j]);
  }
  float o[H];
  #pragma unroll
  for (int j=0;j<H;j++) o[j] = b2[j];
  #pragma unroll
  for (int k=0;k<H;k++){
    float hk = relu_(hid[k]);
    #pragma unroll
    for (int j=0;j<H;j++) o[j] = fmaf(hk, w2[k*H+j], o[j]);
  }
  float4* hw = (float4*)(h + (size_t)v*H);
  #pragma unroll
  for (int j4=0;j4<H/4;j4++){
    float4 t;
    t.x = relu_(o[4*j4+0]); t.y = relu_(o[4*j4+1]);
    t.z = relu_(o[4*j4+2]); t.w = relu_(o[4*j4+3]);
    hw[j4] = t;
  }
}

// ---------------- in-degree counts ----------------
__global__ __launch_bounds__(256) void deg_kernel(const int* __restrict__ dst,
                                                  int* __restrict__ counts)
{
  int e = blockIdx.x*256 + threadIdx.x;
  if (e < NE) atomicAdd(&counts[dst[e]], 1);
}

// ---------------- per-edge message MLP + scatter-add ----------------
__global__ __launch_bounds__(256) void msg_kernel(
    const float* __restrict__ h,
    const int* __restrict__ src, const int* __restrict__ dst,
    const float* __restrict__ w1, const float* __restrict__ b1,
    const float* __restrict__ w2, const float* __restrict__ b2,
    float* __restrict__ agg)
{
  int e = blockIdx.x*256 + threadIdx.x;
  if (e >= NE) return;
  int s = src[e], d = dst[e];
  const float4* hs = (const float4*)(h + (size_t)s*H);
  const float4* hd = (const float4*)(h + (size_t)d*H);

  float hid[H];
  #pragma unroll
  for (int j=0;j<H;j++) hid[j] = b1[j];

  // first half of input: h[src] -> w1 rows 0..63
  #pragma unroll 4
  for (int k4=0;k4<16;k4++){
    float4 a = hs[k4];
    const float* wr = w1 + (size_t)(4*k4)*H;
    #pragma unroll
    for (int j=0;j<H;j++) hid[j] = fmaf(a.x, wr[j], hid[j]);
    #pragma unroll
    for (int j=0;j<H;j++) hid[j] = fmaf(a.y, wr[H+j], hid[j]);
    #pragma unroll
    for (int j=0;j<H;j++) hid[j] = fmaf(a.z, wr[2*H+j], hid[j]);
    #pragma unroll
    for (int j=0;j<H;j++) hid[j] = fmaf(a.w, wr[3*H+j], hid[j]);
  }
  // second half of input: h[dst] -> w1 rows 64..127
  #pragma unroll 4
  for (int k4=0;k4<16;k4++){
    float4 a = hd[k4];
    const float* wr = w1 + (size_t)(64 + 4*k4)*H;
    #pragma unroll
    for (int j=0;j<H;j++) hid[j] = fmaf(a.x, wr[j], hid[j]);
    #pragma unroll
    for (int j=0;j<H;j++) hid[j] = fmaf(a.y, wr[H+j], hid[j]);
    #pragma unroll
    for (int j=0;j<H;j++) hid[j] = fmaf(a.z, wr[2*H+j], hid[j]);
    #pragma unroll
    for (int j=0;j<H;j++) hid[j] = fmaf(a.w, wr[3*H+j], hid[j]);
  }

  float o[H];
  #pragma unroll
  for (int j=0;j<H;j++) o[j] = b2[j];
  #pragma unroll
  for (int k=0;k<H;k++){
    float hk = relu_(hid[k]);
    #pragma unroll
    for (int j=0;j<H;j++) o[j] = fmaf(hk, w2[k*H+j], o[j]);
  }

  float* arow = agg + (size_t)d*H;
  #pragma unroll
  for (int j=0;j<H;j++) atomicAdd(arow + j, relu_(o[j]));
}

// ---------------- per-node update MLP (in-place on h) ----------------
__global__ __launch_bounds__(256) void upd_kernel(
    float* __restrict__ h, const float* __restrict__ agg,
    const int* __restrict__ counts,
    const float* __restrict__ w1, const float* __restrict__ b1,
    const float* __restrict__ w2, const float* __restrict__ b2)
{
  int v = blockIdx.x*256 + threadIdx.x;
  if (v >= NN) return;
  float invd = 1.0f / fmaxf((float)counts[v], 1.0f);
  const float4* hv = (const float4*)(h + (size_t)v*H);
  const float4* av = (const float4*)(agg + (size_t)v*H);

  float hid[H];
  #pragma unroll
  for (int j=0;j<H;j++) hid[j] = b1[j];

  #pragma unroll 4
  for (int k4=0;k4<16;k4++){
    float4 a = hv[k4];
    const float* wr = w1 + (size_t)(4*k4)*H;
    #pragma unroll
    for (int j=0;j<H;j++) hid[j] = fmaf(a.x, wr[j], hid[j]);
    #pragma unroll
    for (int j=0;j<H;j++) hid[j] = fmaf(a.y, wr[H+j], hid[j]);
    #pragma unroll
    for (int j=0;j<H;j++) hid[j] = fmaf(a.z, wr[2*H+j], hid[j]);
    #pragma unroll
    for (int j=0;j<H;j++) hid[j] = fmaf(a.w, wr[3*H+j], hid[j]);
  }
  #pragma unroll 4
  for (int k4=0;k4<16;k4++){
    float4 a = av[k4];
    a.x *= invd; a.y *= invd; a.z *= invd; a.w *= invd;
    const float* wr = w1 + (size_t)(64 + 4*k4)*H;
    #pragma unroll
    for (int j=0;j<H;j++) hid[j] = fmaf(a.x, wr[j], hid[j]);
    #pragma unroll
    for (int j=0;j<H;j++) hid[j] = fmaf(a.y, wr[H+j], hid[j]);
    #pragma unroll
    for (int j=0;j<H;j++) hid[j] = fmaf(a.z, wr[2*H+j], hid[j]);
    #pragma unroll
    for (int j=0;j<H;j++) hid[j] = fmaf(a.w, wr[3*H+j], hid[j]);
  }

  float o[H];
  #pragma unroll
  for (int j=0;j<H;j++) o[j] = b2[j];
  #pragma unroll
  for (int k=0;k<H;k++){
    float hk = relu_(hid[k]);
    #pragma unroll
    for (int j=0;j<H;j++) o[j] = fmaf(hk, w2[k*H+j], o[j]);
  }

  float4* hw = (float4*)(h + (size_t)v*H);
  #pragma unroll
  for (int j4=0;j4<H/4;j4++){
    float4 t;
    t.x = relu_(o[4*j4+0]); t.y = relu_(o[4*j4+1]);
    t.z = relu_(o[4*j4+2]); t.w = relu_(o[4*j4+3]);
    hw[j4] = t;
  }
}

// ---------------- output head: 2*pi*sigmoid(relu(h@w1+b1)@w2+b2) ----------------
__global__ __launch_bounds__(256) void out_kernel(
    const float* __restrict__ h,
    const float* __restrict__ w1, const float* __restrict__ b1,
    const float* __restrict__ w2, const float* __restrict__ b2,
    float* __restrict__ out)
{
  int v = blockIdx.x*256 + threadIdx.x;
  if (v >= NN) return;
  const float4* hv = (const float4*)(h + (size_t)v*H);

  float hid[H];
  #pragma unroll
  for (int j=0;j<H;j++) hid[j] = b1[j];
  #pragma unroll 4
  for (int k4=0;k4<16;k4++){
    float4 a = hv[k4];
    const float* wr = w1 + (size_t)(4*k4)*H;
    #pragma unroll
    for (int j=0;j<H;j++) hid[j] = fmaf(a.x, wr[j], hid[j]);
    #pragma unroll
    for (int j=0;j<H;j++) hid[j] = fmaf(a.y, wr[H+j], hid[j]);
    #pragma unroll
    for (int j=0;j<H;j++) hid[j] = fmaf(a.z, wr[2*H+j], hid[j]);
    #pragma unroll
    for (int j=0;j<H;j++) hid[j] = fmaf(a.w, wr[3*H+j], hid[j]);
  }

  float p[3];
  #pragma unroll
  for (int c=0;c<3;c++) p[c] = b2[c];
  #pragma unroll
  for (int k=0;k<H;k++){
    float hk = relu_(hid[k]);
    #pragma unroll
    for (int c=0;c<3;c++) p[c] = fmaf(hk, w2[k*3+c], p[c]);
  }
  #pragma unroll
  for (int c=0;c<3;c++)
    out[(size_t)v*3+c] = 6.283185307179586f / (1.0f + __expf(-p[c]));
}

extern "C" void kernel_launch(void* const* d_in, const int* in_sizes, int n_in,
                              void* d_out, int out_size, void* d_ws, size_t ws_size,
                              hipStream_t stream)
{
  const float* x      = (const float*)d_in[0];
  const int*   ei     = (const int*)  d_in[1];
  const float* enc_w1 = (const float*)d_in[2];
  const float* enc_b1 = (const float*)d_in[3];
  const float* enc_w2 = (const float*)d_in[4];
  const float* enc_b2 = (const float*)d_in[5];
  const float* msg_w1 = (const float*)d_in[6];
  const float* msg_b1 = (const float*)d_in[7];
  const float* msg_w2 = (const float*)d_in[8];
  const float* msg_b2 = (const float*)d_in[9];
  const float* upd_w1 = (const float*)d_in[10];
  const float* upd_b1 = (const float*)d_in[11];
  const float* upd_w2 = (const float*)d_in[12];
  const float* upd_b2 = (const float*)d_in[13];
  const float* out_w1 = (const float*)d_in[14];
  const float* out_b1 = (const float*)d_in[15];
  const float* out_w2 = (const float*)d_in[16];
  const float* out_b2 = (const float*)d_in[17];
  float* out = (float*)d_out;

  // workspace layout: h [NN*64] f32 | agg [NN*64] f32 | counts [NN] i32
  float* h      = (float*)d_ws;
  float* agg    = h + (size_t)NN*H;
  int*   counts = (int*)(agg + (size_t)NN*H);

  const int* srcp = ei;
  const int* dstp = ei + NE;

  const int nodeBlocks = (NN + 255)/256;
  const int edgeBlocks = (NE + 255)/256;

  hipMemsetAsync(counts, 0, NN*sizeof(int), stream);
  enc_kernel<<<nodeBlocks, 256, 0, stream>>>(x, enc_w1, enc_b1, enc_w2, enc_b2, h);
  deg_kernel<<<edgeBlocks, 256, 0, stream>>>(dstp, counts);

  for (int l=0; l<3; l++){
    hipMemsetAsync(agg, 0, (size_t)NN*H*sizeof(float), stream);
    msg_kernel<<<edgeBlocks, 256, 0, stream>>>(h, srcp, dstp,
        msg_w1 + (size_t)l*128*H, msg_b1 + (size_t)l*H,
        msg_w2 + (size_t)l*H*H,   msg_b2 + (size_t)l*H, agg);
    upd_kernel<<<nodeBlocks, 256, 0, stream>>>(h, agg, counts,
        upd_w1 + (size_t)l*128*H, upd_b1 + (size_t)l*H,
        upd_w2 + (size_t)l*H*H,   upd_b2 + (size_t)l*H);
  }

  out_kernel<<<nodeBlocks, 256, 0, stream>>>(h, out_w1, out_b1, out_w2, out_b2, out);
}